// Round 1
// baseline (1185.489 us; speedup 1.0000x reference)
//
#include <hip/hip_runtime.h>
#include <hip/hip_bf16.h>
#include <math.h>

// MultiBoxLoss (SSD) on MI355X.
// Inputs: loc_pred [B,A,4] f32, conf_pred [B,A,2] f32, gt_boxes [B,4] f32,
//         anchors [A,4] f32 (center-size).
// Outputs (8 f32): loss_loc, loss_cls, pos_acc, neg_acc, position_error,
//                  size_err0, size_err1, N.
// Key insight: loc_pred only read at positive anchors (~0.1%); mining done by
// per-row radix-select on ce bit patterns (non-negative float order == uint order).

#define MAXB 64  // B=64 in this problem; accumulator arrays sized statically

struct Accum {
  int row_np[MAXB];            // per-row positive counts
  unsigned int row_thr[MAXB];  // k-th largest ce (bit pattern)
  int row_need_eq[MAXB];       // how many ties at threshold to take
  int row_eq_taken[MAXB];      // arrival counter for ties
  float loc_sum;
  float cls_pos_sum;
  float cls_neg_sum;
  float perr_sum;
  float serr0;
  float serr1;
  int pos_correct;
  int neg_correct;
  int neg_total;
};

__device__ __forceinline__ float iou_f(float4 g, float4 an) {
  // g: point form gt; an: center-size anchor
  float ax0 = an.x - an.z * 0.5f, ay0 = an.y - an.w * 0.5f;
  float ax1 = an.x + an.z * 0.5f, ay1 = an.y + an.w * 0.5f;
  float ltx = fmaxf(g.x, ax0), lty = fmaxf(g.y, ay0);
  float rbx = fminf(g.z, ax1), rby = fminf(g.w, ay1);
  float w = fmaxf(rbx - ltx, 0.f), h = fmaxf(rby - lty, 0.f);
  float inter = w * h;
  float area_g = (g.z - g.x) * (g.w - g.y);
  float area_a = (ax1 - ax0) * (ay1 - ay0);
  return inter / (area_g + area_a - inter);
}

// ce = nll(target=0) for neg0 anchors (IoU <= 0.3), else 0. Returned as the
// uint bit pattern (monotone order for non-negative floats).
__device__ __forceinline__ unsigned int ce_key_f(float ov, float c0, float c1) {
  bool pos = ov >= 0.6f;
  bool ign = (ov > 0.3f) & (ov < 0.6f);
  if (pos | ign) return 0u;
  float m = fmaxf(c0, c1);
  float s = logf(expf(c0 - m) + expf(c1 - m));
  float ce = (m - c0) + s;
  return __float_as_uint(ce);
}

__device__ __forceinline__ float sl1(float x) {
  float ax = fabsf(x);
  return ax < 1.f ? 0.5f * x * x : ax - 0.5f;
}

__global__ void k_init(Accum* acc) {
  int n = (int)(sizeof(Accum) / 4);
  int* p = (int*)acc;
  for (int i = threadIdx.x; i < n; i += blockDim.x) p[i] = 0;
}

// Pass 1: per-anchor labels, nll, positive-side losses & diagnostics.
// grid = (A/256, B), block = 256. A assumed divisible by 256 (A=65536).
__global__ __launch_bounds__(256) void k_main(
    const float* __restrict__ loc_pred, const float* __restrict__ conf,
    const float* __restrict__ gt, const float* __restrict__ anchors,
    Accum* __restrict__ acc, int A) {
  int b = blockIdx.y;
  int a = blockIdx.x * 256 + threadIdx.x;
  long long ia = (long long)b * A + a;
  float4 g = reinterpret_cast<const float4*>(gt)[b];
  float4 an = reinterpret_cast<const float4*>(anchors)[a];
  float ov = iou_f(g, an);
  bool pos = ov >= 0.6f;
  float2 c = reinterpret_cast<const float2*>(conf)[ia];
  float m = fmaxf(c.x, c.y);
  float s = logf(expf(c.x - m) + expf(c.y - m));

  float loc_s = 0.f, clsp = 0.f, perr = 0.f, se0 = 0.f, se1 = 0.f;
  int pcnt = pos ? 1 : 0, pcor = 0;
  if (pos) {
    float4 lp = reinterpret_cast<const float4*>(loc_pred)[ia];
    // encode(gt, anchor)
    float gcx = (g.x + g.z) * 0.5f, gcy = (g.y + g.w) * 0.5f;
    float gw = g.z - g.x, gh = g.w - g.y;
    float t0 = (gcx - an.x) / (0.1f * an.z);
    float t1 = (gcy - an.y) / (0.1f * an.w);
    float t2 = logf(gw / an.z) / 0.2f;
    float t3 = logf(gh / an.w) / 0.2f;
    loc_s = sl1(lp.x - t0) + sl1(lp.y - t1) + sl1(lp.z - t2) + sl1(lp.w - t3);
    clsp = (m - c.y) + s;          // nll with tgt=1
    pcor = (c.y > c.x) ? 1 : 0;    // argmax==1 (ties -> 0)
    // decode(loc_pred, anchor)
    float dcx = an.x + lp.x * 0.1f * an.z;
    float dcy = an.y + lp.y * 0.1f * an.w;
    float dw = an.z * expf(lp.z * 0.2f);
    float dh = an.w * expf(lp.w * 0.2f);
    float dx0 = dcx - dw * 0.5f, dy0 = dcy - dh * 0.5f;
    float ex = (g.x - dx0) * 255.f, ey = (g.y - dy0) * 255.f;
    perr = sqrtf(ex * ex + ey * ey);
    se0 = fabsf(g.z - (dx0 + dw));
    se1 = fabsf(g.w - (dy0 + dh));
  }

  // block reduce (4 waves of 64)
  __shared__ float smf[5][4];
  __shared__ int smi[2][4];
  int lane = threadIdx.x & 63, wv = threadIdx.x >> 6;
  float fv[5] = {loc_s, clsp, perr, se0, se1};
  int iv[2] = {pcnt, pcor};
#pragma unroll
  for (int q = 0; q < 5; ++q) {
    float v = fv[q];
#pragma unroll
    for (int o = 32; o > 0; o >>= 1) v += __shfl_down(v, o, 64);
    if (lane == 0) smf[q][wv] = v;
  }
#pragma unroll
  for (int q = 0; q < 2; ++q) {
    int v = iv[q];
#pragma unroll
    for (int o = 32; o > 0; o >>= 1) v += __shfl_down(v, o, 64);
    if (lane == 0) smi[q][wv] = v;
  }
  __syncthreads();
  if (threadIdx.x == 0) {
    float L = 0, C = 0, P = 0, S0 = 0, S1 = 0;
    int PC = 0, COR = 0;
    for (int w2 = 0; w2 < 4; ++w2) {
      L += smf[0][w2]; C += smf[1][w2]; P += smf[2][w2];
      S0 += smf[3][w2]; S1 += smf[4][w2];
      PC += smi[0][w2]; COR += smi[1][w2];
    }
    if (PC > 0) {  // only blocks containing positives touch the atomics
      atomicAdd(&acc->row_np[b], PC);
      atomicAdd(&acc->loc_sum, L);
      atomicAdd(&acc->cls_pos_sum, C);
      atomicAdd(&acc->perr_sum, P);
      atomicAdd(&acc->serr0, S0);
      atomicAdd(&acc->serr1, S1);
      atomicAdd(&acc->pos_correct, COR);
    }
  }
}

// Pass 2: per-row radix select of the k-th largest ce. One block per row.
__global__ __launch_bounds__(256) void k_thr(
    const float* __restrict__ conf, const float* __restrict__ gt,
    const float* __restrict__ anchors, Accum* __restrict__ acc, int A) {
  int b = blockIdx.x;
  __shared__ unsigned int hist[256];
  __shared__ unsigned int s_prefix;
  __shared__ int s_kr;
  float4 g = reinterpret_cast<const float4*>(gt)[b];
  int np = acc->row_np[b];
  int k = 3 * np;
  if (k < 10) k = 10;
  if (k > A - 1) k = A - 1;
  unsigned int prefix = 0u;
  int kr = k;
  const float2* crow = reinterpret_cast<const float2*>(conf) + (long long)b * A;
  for (int pass = 0; pass < 4; ++pass) {
    int shift = 24 - 8 * pass;
    unsigned int himask = (pass == 0) ? 0u : (0xFFFFFFFFu << (shift + 8));
    hist[threadIdx.x] = 0u;
    __syncthreads();
    for (int a = threadIdx.x; a < A; a += 256) {
      float4 an = reinterpret_cast<const float4*>(anchors)[a];
      float ov = iou_f(g, an);
      float2 c = crow[a];
      unsigned int key = ce_key_f(ov, c.x, c.y);
      if ((key & himask) == prefix) atomicAdd(&hist[(key >> shift) & 255], 1u);
    }
    __syncthreads();
    if (threadIdx.x == 0) {
      int kk = kr;
      int bin = 255;
      for (int i = 255; i >= 0; --i) {
        int cc = (int)hist[i];
        if (kk <= cc) { bin = i; break; }
        kk -= cc;
      }
      s_prefix = prefix | ((unsigned int)bin << shift);
      s_kr = kk;
    }
    __syncthreads();
    prefix = s_prefix;
    kr = s_kr;
    __syncthreads();
  }
  if (threadIdx.x == 0) {
    acc->row_thr[b] = prefix;
    acc->row_need_eq[b] = kr;
  }
}

// Pass 3: select negatives (key > thr, plus need_eq ties), accumulate cls-neg
// loss and neg accuracy. grid = (A/256, B).
__global__ __launch_bounds__(256) void k_neg(
    const float* __restrict__ conf, const float* __restrict__ gt,
    const float* __restrict__ anchors, Accum* __restrict__ acc, int A) {
  int b = blockIdx.y;
  int a = blockIdx.x * 256 + threadIdx.x;
  long long ia = (long long)b * A + a;
  float4 g = reinterpret_cast<const float4*>(gt)[b];
  float4 an = reinterpret_cast<const float4*>(anchors)[a];
  float ov = iou_f(g, an);
  float2 c = reinterpret_cast<const float2*>(conf)[ia];
  unsigned int key = ce_key_f(ov, c.x, c.y);
  unsigned int t = acc->row_thr[b];
  int sel = 0;
  if (key > t) {
    sel = 1;
  } else if (key == t) {
    int ord = atomicAdd(&acc->row_eq_taken[b], 1);
    if (ord < acc->row_need_eq[b]) sel = 1;
  }
  float cls = 0.f;
  int ncnt = 0, ncor = 0;
  if (sel) {
    ncnt = 1;
    cls = __uint_as_float(key);
    ncor = (c.y > c.x) ? 0 : 1;  // pred_cls==0 correct for a negative
  }
  __shared__ float smf[4];
  __shared__ int smi[2][4];
  int lane = threadIdx.x & 63, wv = threadIdx.x >> 6;
  {
    float v = cls;
#pragma unroll
    for (int o = 32; o > 0; o >>= 1) v += __shfl_down(v, o, 64);
    if (lane == 0) smf[wv] = v;
  }
  {
    int v = ncnt;
#pragma unroll
    for (int o = 32; o > 0; o >>= 1) v += __shfl_down(v, o, 64);
    if (lane == 0) smi[0][wv] = v;
  }
  {
    int v = ncor;
#pragma unroll
    for (int o = 32; o > 0; o >>= 1) v += __shfl_down(v, o, 64);
    if (lane == 0) smi[1][wv] = v;
  }
  __syncthreads();
  if (threadIdx.x == 0) {
    float C = smf[0] + smf[1] + smf[2] + smf[3];
    int NC = smi[0][0] + smi[0][1] + smi[0][2] + smi[0][3];
    int COR = smi[1][0] + smi[1][1] + smi[1][2] + smi[1][3];
    if (NC > 0) {
      atomicAdd(&acc->cls_neg_sum, C);
      atomicAdd(&acc->neg_total, NC);
      atomicAdd(&acc->neg_correct, COR);
    }
  }
}

__global__ void k_final(const Accum* __restrict__ acc, float* __restrict__ out,
                        int B) {
  int N = 0;
  for (int b = 0; b < B; ++b) N += acc->row_np[b];
  float Nf = fmaxf((float)N, 1.f);
  out[0] = acc->loc_sum / (Nf * 4.f);
  float wsum = (float)N + (float)acc->neg_total * (1.f / 3.f);
  out[1] = (acc->cls_pos_sum + acc->cls_neg_sum * (1.f / 3.f)) / wsum;
  out[2] = (float)acc->pos_correct / (float)(N > 1 ? N : 1);
  out[3] = (float)acc->neg_correct /
           (float)(acc->neg_total > 1 ? acc->neg_total : 1);
  out[4] = acc->perr_sum / Nf;
  out[5] = acc->serr0 / Nf * 255.f;
  out[6] = acc->serr1 / Nf * 255.f;
  out[7] = (float)N;
}

extern "C" void kernel_launch(void* const* d_in, const int* in_sizes, int n_in,
                              void* d_out, int out_size, void* d_ws,
                              size_t ws_size, hipStream_t stream) {
  (void)n_in; (void)out_size; (void)ws_size;
  const float* loc = (const float*)d_in[0];
  const float* conf = (const float*)d_in[1];
  const float* gt = (const float*)d_in[2];
  const float* anchors = (const float*)d_in[3];
  int B = in_sizes[2] / 4;  // 64
  int A = in_sizes[3] / 4;  // 65536
  Accum* acc = (Accum*)d_ws;
  float* out = (float*)d_out;

  k_init<<<1, 256, 0, stream>>>(acc);
  dim3 grid(A / 256, B);
  k_main<<<grid, 256, 0, stream>>>(loc, conf, gt, anchors, acc, A);
  k_thr<<<B, 256, 0, stream>>>(conf, gt, anchors, acc, A);
  k_neg<<<grid, 256, 0, stream>>>(conf, gt, anchors, acc, A);
  k_final<<<1, 1, 0, stream>>>(acc, out, B);
}

// Round 2
// 559.335 us; speedup vs baseline: 2.1195x; 2.1195x over previous
//
#include <hip/hip_runtime.h>
#include <hip/hip_bf16.h>
#include <math.h>

// MultiBoxLoss (SSD) on MI355X.
// R2: grid-parallel radix select (4x8-bit) replaces the 64-block k_thr that
// was 810us at 3% occupancy. Histogram passes recompute keys at full
// occupancy; per-row state (prefix, residual rank) lives in Accum.

#define MAXB 64  // B=64 in this problem

struct Accum {
  int row_np[MAXB];            // per-row positive counts
  unsigned int row_thr[MAXB];  // radix prefix, becomes k-th largest ce bits
  int row_need_eq[MAXB];       // residual rank -> ties to take at threshold
  int row_eq_taken[MAXB];      // arrival counter for ties
  float loc_sum;
  float cls_pos_sum;
  float cls_neg_sum;
  float perr_sum;
  float serr0;
  float serr1;
  int pos_correct;
  int neg_correct;
  int neg_total;
};

__device__ __forceinline__ float iou_f(float4 g, float4 an) {
  float ax0 = an.x - an.z * 0.5f, ay0 = an.y - an.w * 0.5f;
  float ax1 = an.x + an.z * 0.5f, ay1 = an.y + an.w * 0.5f;
  float ltx = fmaxf(g.x, ax0), lty = fmaxf(g.y, ay0);
  float rbx = fminf(g.z, ax1), rby = fminf(g.w, ay1);
  float w = fmaxf(rbx - ltx, 0.f), h = fmaxf(rby - lty, 0.f);
  float inter = w * h;
  float area_g = (g.z - g.x) * (g.w - g.y);
  float area_a = (ax1 - ax0) * (ay1 - ay0);
  return inter / (area_g + area_a - inter);
}

// ce = nll(target=0) for neg0 anchors (IoU <= 0.3), else 0; as uint bits
// (non-negative float order == uint order).
__device__ __forceinline__ unsigned int ce_key_f(float ov, float c0, float c1) {
  bool pos = ov >= 0.6f;
  bool ign = (ov > 0.3f) & (ov < 0.6f);
  if (pos | ign) return 0u;
  float m = fmaxf(c0, c1);
  float s = logf(expf(c0 - m) + expf(c1 - m));
  float ce = (m - c0) + s;
  return __float_as_uint(ce);
}

__device__ __forceinline__ float sl1(float x) {
  float ax = fabsf(x);
  return ax < 1.f ? 0.5f * x * x : ax - 0.5f;
}

__global__ void k_init(Accum* acc, unsigned int* ghist, int B) {
  int* p = (int*)acc;
  int n0 = (int)(sizeof(Accum) / 4);
  for (int i = threadIdx.x; i < n0; i += blockDim.x) p[i] = 0;
  int n1 = B * 256;
  for (int i = threadIdx.x; i < n1; i += blockDim.x) ghist[i] = 0u;
}

// Pass 1: per-anchor labels, nll, positive-side losses & diagnostics.
__global__ __launch_bounds__(256) void k_main(
    const float* __restrict__ loc_pred, const float* __restrict__ conf,
    const float* __restrict__ gt, const float* __restrict__ anchors,
    Accum* __restrict__ acc, int A) {
  int b = blockIdx.y;
  int a = blockIdx.x * 256 + threadIdx.x;
  long long ia = (long long)b * A + a;
  float4 g = reinterpret_cast<const float4*>(gt)[b];
  float4 an = reinterpret_cast<const float4*>(anchors)[a];
  float ov = iou_f(g, an);
  bool pos = ov >= 0.6f;
  float2 c = reinterpret_cast<const float2*>(conf)[ia];
  float m = fmaxf(c.x, c.y);
  float s = logf(expf(c.x - m) + expf(c.y - m));

  float loc_s = 0.f, clsp = 0.f, perr = 0.f, se0 = 0.f, se1 = 0.f;
  int pcnt = pos ? 1 : 0, pcor = 0;
  if (pos) {
    float4 lp = reinterpret_cast<const float4*>(loc_pred)[ia];
    float gcx = (g.x + g.z) * 0.5f, gcy = (g.y + g.w) * 0.5f;
    float gw = g.z - g.x, gh = g.w - g.y;
    float t0 = (gcx - an.x) / (0.1f * an.z);
    float t1 = (gcy - an.y) / (0.1f * an.w);
    float t2 = logf(gw / an.z) / 0.2f;
    float t3 = logf(gh / an.w) / 0.2f;
    loc_s = sl1(lp.x - t0) + sl1(lp.y - t1) + sl1(lp.z - t2) + sl1(lp.w - t3);
    clsp = (m - c.y) + s;
    pcor = (c.y > c.x) ? 1 : 0;
    float dcx = an.x + lp.x * 0.1f * an.z;
    float dcy = an.y + lp.y * 0.1f * an.w;
    float dw = an.z * expf(lp.z * 0.2f);
    float dh = an.w * expf(lp.w * 0.2f);
    float dx0 = dcx - dw * 0.5f, dy0 = dcy - dh * 0.5f;
    float ex = (g.x - dx0) * 255.f, ey = (g.y - dy0) * 255.f;
    perr = sqrtf(ex * ex + ey * ey);
    se0 = fabsf(g.z - (dx0 + dw));
    se1 = fabsf(g.w - (dy0 + dh));
  }

  __shared__ float smf[5][4];
  __shared__ int smi[2][4];
  int lane = threadIdx.x & 63, wv = threadIdx.x >> 6;
  float fv[5] = {loc_s, clsp, perr, se0, se1};
  int iv[2] = {pcnt, pcor};
#pragma unroll
  for (int q = 0; q < 5; ++q) {
    float v = fv[q];
#pragma unroll
    for (int o = 32; o > 0; o >>= 1) v += __shfl_down(v, o, 64);
    if (lane == 0) smf[q][wv] = v;
  }
#pragma unroll
  for (int q = 0; q < 2; ++q) {
    int v = iv[q];
#pragma unroll
    for (int o = 32; o > 0; o >>= 1) v += __shfl_down(v, o, 64);
    if (lane == 0) smi[q][wv] = v;
  }
  __syncthreads();
  if (threadIdx.x == 0) {
    float L = 0, C = 0, P = 0, S0 = 0, S1 = 0;
    int PC = 0, COR = 0;
    for (int w2 = 0; w2 < 4; ++w2) {
      L += smf[0][w2]; C += smf[1][w2]; P += smf[2][w2];
      S0 += smf[3][w2]; S1 += smf[4][w2];
      PC += smi[0][w2]; COR += smi[1][w2];
    }
    if (PC > 0) {
      atomicAdd(&acc->row_np[b], PC);
      atomicAdd(&acc->loc_sum, L);
      atomicAdd(&acc->cls_pos_sum, C);
      atomicAdd(&acc->perr_sum, P);
      atomicAdd(&acc->serr0, S0);
      atomicAdd(&acc->serr1, S1);
      atomicAdd(&acc->pos_correct, COR);
    }
  }
}

// Radix histogram pass: grid (A/256, B). Counts keys matching the current
// per-row prefix into ghist[b][256] (LDS pre-aggregated).
__global__ __launch_bounds__(256) void k_hist(
    const float* __restrict__ conf, const float* __restrict__ gt,
    const float* __restrict__ anchors, Accum* __restrict__ acc,
    unsigned int* __restrict__ ghist, int A, int shift,
    unsigned int himask) {
  int b = blockIdx.y;
  int a = blockIdx.x * 256 + threadIdx.x;
  long long ia = (long long)b * A + a;
  __shared__ unsigned int hist[256];
  hist[threadIdx.x] = 0u;
  __syncthreads();
  float4 g = reinterpret_cast<const float4*>(gt)[b];
  float4 an = reinterpret_cast<const float4*>(anchors)[a];
  float ov = iou_f(g, an);
  float2 c = reinterpret_cast<const float2*>(conf)[ia];
  unsigned int key = ce_key_f(ov, c.x, c.y);
  unsigned int prefix = acc->row_thr[b];
  if ((key & himask) == prefix) atomicAdd(&hist[(key >> shift) & 255], 1u);
  __syncthreads();
  unsigned int h = hist[threadIdx.x];
  if (h) atomicAdd(&ghist[b * 256 + threadIdx.x], h);
}

// Pick the bin holding the k-th largest key; update prefix & residual rank;
// zero ghist row for the next pass. One block per row.
__global__ __launch_bounds__(256) void k_pick(Accum* __restrict__ acc,
                                              unsigned int* __restrict__ ghist,
                                              int A, int shift, int pass0) {
  int b = blockIdx.x;
  __shared__ unsigned int h[256];
  h[threadIdx.x] = ghist[b * 256 + threadIdx.x];
  ghist[b * 256 + threadIdx.x] = 0u;
  __syncthreads();
  if (threadIdx.x == 0) {
    int kr;
    if (pass0) {
      int k = 3 * acc->row_np[b];
      if (k < 10) k = 10;
      if (k > A - 1) k = A - 1;
      kr = k;
    } else {
      kr = acc->row_need_eq[b];
    }
    int bin = 255;
    for (int i = 255; i >= 0; --i) {
      int cc = (int)h[i];
      if (kr <= cc) { bin = i; break; }
      kr -= cc;
    }
    acc->row_thr[b] |= ((unsigned int)bin << shift);
    acc->row_need_eq[b] = kr;
  }
}

// Select negatives (key > thr, plus need_eq ties), accumulate cls-neg loss
// and neg accuracy. grid = (A/256, B).
__global__ __launch_bounds__(256) void k_neg(
    const float* __restrict__ conf, const float* __restrict__ gt,
    const float* __restrict__ anchors, Accum* __restrict__ acc, int A) {
  int b = blockIdx.y;
  int a = blockIdx.x * 256 + threadIdx.x;
  long long ia = (long long)b * A + a;
  float4 g = reinterpret_cast<const float4*>(gt)[b];
  float4 an = reinterpret_cast<const float4*>(anchors)[a];
  float ov = iou_f(g, an);
  float2 c = reinterpret_cast<const float2*>(conf)[ia];
  unsigned int key = ce_key_f(ov, c.x, c.y);
  unsigned int t = acc->row_thr[b];
  int sel = 0;
  if (key > t) {
    sel = 1;
  } else if (key == t) {
    int ord = atomicAdd(&acc->row_eq_taken[b], 1);
    if (ord < acc->row_need_eq[b]) sel = 1;
  }
  float cls = 0.f;
  int ncnt = 0, ncor = 0;
  if (sel) {
    ncnt = 1;
    cls = __uint_as_float(key);
    ncor = (c.y > c.x) ? 0 : 1;
  }
  __shared__ float smf[4];
  __shared__ int smi[2][4];
  int lane = threadIdx.x & 63, wv = threadIdx.x >> 6;
  {
    float v = cls;
#pragma unroll
    for (int o = 32; o > 0; o >>= 1) v += __shfl_down(v, o, 64);
    if (lane == 0) smf[wv] = v;
  }
  {
    int v = ncnt;
#pragma unroll
    for (int o = 32; o > 0; o >>= 1) v += __shfl_down(v, o, 64);
    if (lane == 0) smi[0][wv] = v;
  }
  {
    int v = ncor;
#pragma unroll
    for (int o = 32; o > 0; o >>= 1) v += __shfl_down(v, o, 64);
    if (lane == 0) smi[1][wv] = v;
  }
  __syncthreads();
  if (threadIdx.x == 0) {
    float C = smf[0] + smf[1] + smf[2] + smf[3];
    int NC = smi[0][0] + smi[0][1] + smi[0][2] + smi[0][3];
    int COR = smi[1][0] + smi[1][1] + smi[1][2] + smi[1][3];
    if (NC > 0) {
      atomicAdd(&acc->cls_neg_sum, C);
      atomicAdd(&acc->neg_total, NC);
      atomicAdd(&acc->neg_correct, COR);
    }
  }
}

__global__ void k_final(const Accum* __restrict__ acc, float* __restrict__ out,
                        int B) {
  int N = 0;
  for (int b = 0; b < B; ++b) N += acc->row_np[b];
  float Nf = fmaxf((float)N, 1.f);
  out[0] = acc->loc_sum / (Nf * 4.f);
  float wsum = (float)N + (float)acc->neg_total * (1.f / 3.f);
  out[1] = (acc->cls_pos_sum + acc->cls_neg_sum * (1.f / 3.f)) / wsum;
  out[2] = (float)acc->pos_correct / (float)(N > 1 ? N : 1);
  out[3] = (float)acc->neg_correct /
           (float)(acc->neg_total > 1 ? acc->neg_total : 1);
  out[4] = acc->perr_sum / Nf;
  out[5] = acc->serr0 / Nf * 255.f;
  out[6] = acc->serr1 / Nf * 255.f;
  out[7] = (float)N;
}

extern "C" void kernel_launch(void* const* d_in, const int* in_sizes, int n_in,
                              void* d_out, int out_size, void* d_ws,
                              size_t ws_size, hipStream_t stream) {
  (void)n_in; (void)out_size; (void)ws_size;
  const float* loc = (const float*)d_in[0];
  const float* conf = (const float*)d_in[1];
  const float* gt = (const float*)d_in[2];
  const float* anchors = (const float*)d_in[3];
  int B = in_sizes[2] / 4;  // 64
  int A = in_sizes[3] / 4;  // 65536
  Accum* acc = (Accum*)d_ws;
  unsigned int* ghist =
      (unsigned int*)((char*)d_ws + ((sizeof(Accum) + 255) & ~255));
  float* out = (float*)d_out;

  k_init<<<1, 256, 0, stream>>>(acc, ghist, B);
  dim3 grid(A / 256, B);
  k_main<<<grid, 256, 0, stream>>>(loc, conf, gt, anchors, acc, A);
  for (int pass = 0; pass < 4; ++pass) {
    int shift = 24 - 8 * pass;
    unsigned int himask =
        (pass == 0) ? 0u : (0xFFFFFFFFu << (shift + 8));
    k_hist<<<grid, 256, 0, stream>>>(conf, gt, anchors, acc, ghist, A, shift,
                                     himask);
    k_pick<<<B, 256, 0, stream>>>(acc, ghist, A, shift, pass == 0);
  }
  k_neg<<<grid, 256, 0, stream>>>(conf, gt, anchors, acc, A);
  k_final<<<1, 1, 0, stream>>>(acc, out, B);
}

// Round 3
// 208.858 us; speedup vs baseline: 5.6761x; 2.6781x over previous
//
#include <hip/hip_runtime.h>
#include <hip/hip_bf16.h>
#include <math.h>

// MultiBoxLoss (SSD) on MI355X.
// R3: (a) slot-spread global accumulators (1024 slots) — R2's k_neg spent
// 279us serializing ~28K device-scope atomicAdds on 3 addresses (evidence:
// WRITE_SIZE=731KB for a 12-byte logical output, VALUBusy 5.5%).
// (b) keys cached in ws by k_main (ce bits | argmax<<31); hist/neg passes are
// key-only readers, 8 elems/thread. Runtime fallback recomputes if ws small.

#define MAXB 64
#define NS 1024  // accumulator slots

struct Accum {
  int row_np[MAXB];
  unsigned int row_thr[MAXB];
  int row_need_eq[MAXB];
  int row_eq_taken[MAXB];
  float f_loc[NS], f_clsp[NS], f_perr[NS], f_se0[NS], f_se1[NS], f_clsn[NS];
  int i_pcor[NS], i_ncor[NS], i_ntot[NS];
};

__device__ __forceinline__ float iou_f(float4 g, float4 an) {
  float ax0 = an.x - an.z * 0.5f, ay0 = an.y - an.w * 0.5f;
  float ax1 = an.x + an.z * 0.5f, ay1 = an.y + an.w * 0.5f;
  float ltx = fmaxf(g.x, ax0), lty = fmaxf(g.y, ay0);
  float rbx = fminf(g.z, ax1), rby = fminf(g.w, ay1);
  float w = fmaxf(rbx - ltx, 0.f), h = fmaxf(rby - lty, 0.f);
  float inter = w * h;
  float area_g = (g.z - g.x) * (g.w - g.y);
  float area_a = (ax1 - ax0) * (ay1 - ay0);
  return inter / (area_g + area_a - inter);
}

// Key: ce bits (ce = nll(tgt=0) if IoU<=0.3 else 0) in bits 0..30, argmax
// (c1>c0) in bit 31. Non-negative float order == uint order on masked bits.
__device__ __forceinline__ unsigned int ce_key_f(float ov, float c0, float c1) {
  unsigned int key = 0u;
  if (ov <= 0.3f) {
    float m = fmaxf(c0, c1);
    float s = logf(expf(c0 - m) + expf(c1 - m));
    key = __float_as_uint((m - c0) + s);
  }
  if (c1 > c0) key |= 0x80000000u;
  return key;
}

__device__ __forceinline__ float sl1(float x) {
  float ax = fabsf(x);
  return ax < 1.f ? 0.5f * x * x : ax - 0.5f;
}

__global__ void k_init(Accum* acc, unsigned int* ghist, int B) {
  int n0 = (int)(sizeof(Accum) / 4);
  int n1 = B * 256;
  int idx = blockIdx.x * blockDim.x + threadIdx.x;
  int stride = gridDim.x * blockDim.x;
  int* p = (int*)acc;
  for (int i = idx; i < n0; i += stride) p[i] = 0;
  for (int i = idx; i < n1; i += stride) ghist[i] = 0u;
}

// Pass 1: labels, nll, positive losses & diagnostics; writes keys (if CACHED).
// grid = (A/1024, B), 4 anchors/thread.
template <bool CACHED>
__global__ __launch_bounds__(256) void k_main(
    const float* __restrict__ loc_pred, const float* __restrict__ conf,
    const float* __restrict__ gt, const float* __restrict__ anchors,
    Accum* __restrict__ acc, unsigned int* __restrict__ keys, int A) {
  int b = blockIdx.y;
  int a0 = (blockIdx.x * 256 + threadIdx.x) * 4;
  long long ia0 = (long long)b * A + a0;
  float4 g = reinterpret_cast<const float4*>(gt)[b];
  const float4* an4 = reinterpret_cast<const float4*>(anchors) + a0;
  float4 c01 = reinterpret_cast<const float4*>(conf)[ia0 >> 1];
  float4 c23 = reinterpret_cast<const float4*>(conf)[(ia0 >> 1) + 1];
  float c0s[4] = {c01.x, c01.z, c23.x, c23.z};
  float c1s[4] = {c01.y, c01.w, c23.y, c23.w};

  float loc_s = 0.f, clsp = 0.f, perr = 0.f, se0 = 0.f, se1 = 0.f;
  int pcnt = 0, pcor = 0;
  unsigned int kout[4];
#pragma unroll
  for (int j = 0; j < 4; ++j) {
    float4 an = an4[j];
    float ov = iou_f(g, an);
    float c0 = c0s[j], c1 = c1s[j];
    kout[j] = ce_key_f(ov, c0, c1);
    if (ov >= 0.6f) {
      float4 lp = reinterpret_cast<const float4*>(loc_pred)[ia0 + j];
      float gcx = (g.x + g.z) * 0.5f, gcy = (g.y + g.w) * 0.5f;
      float gw = g.z - g.x, gh = g.w - g.y;
      float t0 = (gcx - an.x) / (0.1f * an.z);
      float t1 = (gcy - an.y) / (0.1f * an.w);
      float t2 = logf(gw / an.z) / 0.2f;
      float t3 = logf(gh / an.w) / 0.2f;
      loc_s += sl1(lp.x - t0) + sl1(lp.y - t1) + sl1(lp.z - t2) + sl1(lp.w - t3);
      float m = fmaxf(c0, c1);
      float s = logf(expf(c0 - m) + expf(c1 - m));
      clsp += (m - c1) + s;
      pcnt += 1;
      pcor += (c1 > c0) ? 1 : 0;
      float dcx = an.x + lp.x * 0.1f * an.z;
      float dcy = an.y + lp.y * 0.1f * an.w;
      float dw = an.z * expf(lp.z * 0.2f);
      float dh = an.w * expf(lp.w * 0.2f);
      float dx0 = dcx - dw * 0.5f, dy0 = dcy - dh * 0.5f;
      float ex = (g.x - dx0) * 255.f, ey = (g.y - dy0) * 255.f;
      perr += sqrtf(ex * ex + ey * ey);
      se0 += fabsf(g.z - (dx0 + dw));
      se1 += fabsf(g.w - (dy0 + dh));
    }
  }
  if (CACHED) {
    uint4 kv;
    kv.x = kout[0]; kv.y = kout[1]; kv.z = kout[2]; kv.w = kout[3];
    reinterpret_cast<uint4*>(keys)[ia0 >> 2] = kv;
  }

  __shared__ float smf[5][4];
  __shared__ int smi[2][4];
  int lane = threadIdx.x & 63, wv = threadIdx.x >> 6;
  float fv[5] = {loc_s, clsp, perr, se0, se1};
  int iv[2] = {pcnt, pcor};
#pragma unroll
  for (int q = 0; q < 5; ++q) {
    float v = fv[q];
#pragma unroll
    for (int o = 32; o > 0; o >>= 1) v += __shfl_down(v, o, 64);
    if (lane == 0) smf[q][wv] = v;
  }
#pragma unroll
  for (int q = 0; q < 2; ++q) {
    int v = iv[q];
#pragma unroll
    for (int o = 32; o > 0; o >>= 1) v += __shfl_down(v, o, 64);
    if (lane == 0) smi[q][wv] = v;
  }
  __syncthreads();
  if (threadIdx.x == 0) {
    float L = 0, C = 0, P = 0, S0 = 0, S1 = 0;
    int PC = 0, COR = 0;
    for (int w2 = 0; w2 < 4; ++w2) {
      L += smf[0][w2]; C += smf[1][w2]; P += smf[2][w2];
      S0 += smf[3][w2]; S1 += smf[4][w2];
      PC += smi[0][w2]; COR += smi[1][w2];
    }
    if (PC > 0) {
      int slot = (blockIdx.y * gridDim.x + blockIdx.x) & (NS - 1);
      atomicAdd(&acc->row_np[b], PC);
      atomicAdd(&acc->f_loc[slot], L);
      atomicAdd(&acc->f_clsp[slot], C);
      atomicAdd(&acc->f_perr[slot], P);
      atomicAdd(&acc->f_se0[slot], S0);
      atomicAdd(&acc->f_se1[slot], S1);
      atomicAdd(&acc->i_pcor[slot], COR);
    }
  }
}

// Radix histogram pass: grid (A/2048, B), 8 keys/thread, per-wave LDS hist.
template <bool CACHED>
__global__ __launch_bounds__(256) void k_hist(
    const unsigned int* __restrict__ keys, const float* __restrict__ conf,
    const float* __restrict__ gt, const float* __restrict__ anchors,
    Accum* __restrict__ acc, unsigned int* __restrict__ ghist, int A,
    int shift, unsigned int himask) {
  int b = blockIdx.y;
  int tid = threadIdx.x;
  __shared__ unsigned int hist[4][256];
  for (int i = tid; i < 1024; i += 256) ((unsigned int*)hist)[i] = 0u;
  __syncthreads();
  unsigned int prefix = acc->row_thr[b];
  int wv = tid >> 6;
  int i0 = (blockIdx.x * 256 + tid) * 8;
  long long base = (long long)b * A + i0;
  unsigned int km[8];
  if (CACHED) {
    uint4 k0 = reinterpret_cast<const uint4*>(keys)[base >> 2];
    uint4 k1 = reinterpret_cast<const uint4*>(keys)[(base >> 2) + 1];
    km[0] = k0.x; km[1] = k0.y; km[2] = k0.z; km[3] = k0.w;
    km[4] = k1.x; km[5] = k1.y; km[6] = k1.z; km[7] = k1.w;
  } else {
    float4 g = reinterpret_cast<const float4*>(gt)[b];
#pragma unroll
    for (int j = 0; j < 8; ++j) {
      float4 an = reinterpret_cast<const float4*>(anchors)[i0 + j];
      float2 c = reinterpret_cast<const float2*>(conf)[base + j];
      km[j] = ce_key_f(iou_f(g, an), c.x, c.y);
    }
  }
#pragma unroll
  for (int j = 0; j < 8; ++j) {
    unsigned int k = km[j] & 0x7FFFFFFFu;
    if ((k & himask) == prefix) atomicAdd(&hist[wv][(k >> shift) & 255], 1u);
  }
  __syncthreads();
  unsigned int h = hist[0][tid] + hist[1][tid] + hist[2][tid] + hist[3][tid];
  if (h) atomicAdd(&ghist[b * 256 + tid], h);
}

// Pick the k-th-largest bin; update prefix & residual rank; zero ghist row.
__global__ __launch_bounds__(256) void k_pick(Accum* __restrict__ acc,
                                              unsigned int* __restrict__ ghist,
                                              int A, int shift, int pass0) {
  int b = blockIdx.x;
  __shared__ unsigned int h[256];
  h[threadIdx.x] = ghist[b * 256 + threadIdx.x];
  ghist[b * 256 + threadIdx.x] = 0u;
  __syncthreads();
  if (threadIdx.x == 0) {
    int kr;
    if (pass0) {
      int k = 3 * acc->row_np[b];
      if (k < 10) k = 10;
      if (k > A - 1) k = A - 1;
      kr = k;
    } else {
      kr = acc->row_need_eq[b];
    }
    int bin = 255;
    for (int i = 255; i >= 0; --i) {
      int cc = (int)h[i];
      if (kr <= cc) { bin = i; break; }
      kr -= cc;
    }
    acc->row_thr[b] |= ((unsigned int)bin << shift);
    acc->row_need_eq[b] = kr;
  }
}

// Select negatives; accumulate cls-neg loss & neg accuracy via slots.
template <bool CACHED>
__global__ __launch_bounds__(256) void k_neg(
    const unsigned int* __restrict__ keys, const float* __restrict__ conf,
    const float* __restrict__ gt, const float* __restrict__ anchors,
    Accum* __restrict__ acc, int A) {
  int b = blockIdx.y;
  int tid = threadIdx.x;
  unsigned int t = acc->row_thr[b];
  int needeq = acc->row_need_eq[b];
  int i0 = (blockIdx.x * 256 + tid) * 8;
  long long base = (long long)b * A + i0;
  unsigned int kk[8];
  if (CACHED) {
    uint4 k0 = reinterpret_cast<const uint4*>(keys)[base >> 2];
    uint4 k1 = reinterpret_cast<const uint4*>(keys)[(base >> 2) + 1];
    kk[0] = k0.x; kk[1] = k0.y; kk[2] = k0.z; kk[3] = k0.w;
    kk[4] = k1.x; kk[5] = k1.y; kk[6] = k1.z; kk[7] = k1.w;
  } else {
    float4 g = reinterpret_cast<const float4*>(gt)[b];
#pragma unroll
    for (int j = 0; j < 8; ++j) {
      float4 an = reinterpret_cast<const float4*>(anchors)[i0 + j];
      float2 c = reinterpret_cast<const float2*>(conf)[base + j];
      kk[j] = ce_key_f(iou_f(g, an), c.x, c.y);
    }
  }
  float cls = 0.f;
  int ncnt = 0, ncor = 0;
#pragma unroll
  for (int j = 0; j < 8; ++j) {
    unsigned int km = kk[j] & 0x7FFFFFFFu;
    bool s = false;
    if (km > t) {
      s = true;
    } else if (km == t) {
      int ord = atomicAdd(&acc->row_eq_taken[b], 1);
      if (ord < needeq) s = true;
    }
    if (s) {
      cls += __uint_as_float(km);
      ncnt += 1;
      ncor += (int)((kk[j] >> 31) ^ 1u);
    }
  }
  __shared__ float smf[4];
  __shared__ int smi[2][4];
  int lane = tid & 63, wv = tid >> 6;
  {
    float v = cls;
#pragma unroll
    for (int o = 32; o > 0; o >>= 1) v += __shfl_down(v, o, 64);
    if (lane == 0) smf[wv] = v;
  }
  {
    int v = ncnt;
#pragma unroll
    for (int o = 32; o > 0; o >>= 1) v += __shfl_down(v, o, 64);
    if (lane == 0) smi[0][wv] = v;
  }
  {
    int v = ncor;
#pragma unroll
    for (int o = 32; o > 0; o >>= 1) v += __shfl_down(v, o, 64);
    if (lane == 0) smi[1][wv] = v;
  }
  __syncthreads();
  if (tid == 0) {
    float C = smf[0] + smf[1] + smf[2] + smf[3];
    int NC = smi[0][0] + smi[0][1] + smi[0][2] + smi[0][3];
    int COR = smi[1][0] + smi[1][1] + smi[1][2] + smi[1][3];
    if (NC > 0) {
      int slot = (blockIdx.y * gridDim.x + blockIdx.x) & (NS - 1);
      atomicAdd(&acc->f_clsn[slot], C);
      atomicAdd(&acc->i_ntot[slot], NC);
      atomicAdd(&acc->i_ncor[slot], COR);
    }
  }
}

__global__ __launch_bounds__(256) void k_final(const Accum* __restrict__ acc,
                                               float* __restrict__ out, int B) {
  __shared__ float sm[256];
  int t = threadIdx.x;
  float vals[10];
  float s;
  s = 0; for (int i = t; i < NS; i += 256) s += acc->f_loc[i];  vals[0] = s;
  s = 0; for (int i = t; i < NS; i += 256) s += acc->f_clsp[i]; vals[1] = s;
  s = 0; for (int i = t; i < NS; i += 256) s += acc->f_perr[i]; vals[2] = s;
  s = 0; for (int i = t; i < NS; i += 256) s += acc->f_se0[i];  vals[3] = s;
  s = 0; for (int i = t; i < NS; i += 256) s += acc->f_se1[i];  vals[4] = s;
  s = 0; for (int i = t; i < NS; i += 256) s += acc->f_clsn[i]; vals[5] = s;
  s = 0; for (int i = t; i < NS; i += 256) s += (float)acc->i_pcor[i]; vals[6] = s;
  s = 0; for (int i = t; i < NS; i += 256) s += (float)acc->i_ncor[i]; vals[7] = s;
  s = 0; for (int i = t; i < NS; i += 256) s += (float)acc->i_ntot[i]; vals[8] = s;
  s = 0; for (int i = t; i < B;  i += 256) s += (float)acc->row_np[i]; vals[9] = s;
  float tot[10];
  for (int q = 0; q < 10; ++q) {
    sm[t] = vals[q];
    __syncthreads();
    for (int o = 128; o > 0; o >>= 1) {
      if (t < o) sm[t] += sm[t + o];
      __syncthreads();
    }
    tot[q] = sm[0];
    __syncthreads();
  }
  if (t == 0) {
    float N = tot[9];
    float Nf = fmaxf(N, 1.f);
    out[0] = tot[0] / (Nf * 4.f);
    float wsum = N + tot[8] * (1.f / 3.f);
    out[1] = (tot[1] + tot[5] * (1.f / 3.f)) / wsum;
    out[2] = tot[6] / fmaxf(N, 1.f);
    out[3] = tot[7] / fmaxf(tot[8], 1.f);
    out[4] = tot[2] / Nf;
    out[5] = tot[3] / Nf * 255.f;
    out[6] = tot[4] / Nf * 255.f;
    out[7] = N;
  }
}

extern "C" void kernel_launch(void* const* d_in, const int* in_sizes, int n_in,
                              void* d_out, int out_size, void* d_ws,
                              size_t ws_size, hipStream_t stream) {
  (void)n_in; (void)out_size;
  const float* loc = (const float*)d_in[0];
  const float* conf = (const float*)d_in[1];
  const float* gt = (const float*)d_in[2];
  const float* anchors = (const float*)d_in[3];
  int B = in_sizes[2] / 4;  // 64
  int A = in_sizes[3] / 4;  // 65536
  Accum* acc = (Accum*)d_ws;
  size_t accsz = (sizeof(Accum) + 255) & ~(size_t)255;
  size_t ghsz = ((size_t)B * 256 * 4 + 255) & ~(size_t)255;
  unsigned int* ghist = (unsigned int*)((char*)d_ws + accsz);
  unsigned int* keys = (unsigned int*)((char*)d_ws + accsz + ghsz);
  bool cached = ws_size >= accsz + ghsz + (size_t)B * A * 4;
  float* out = (float*)d_out;

  k_init<<<64, 256, 0, stream>>>(acc, ghist, B);
  dim3 gmain(A / 1024, B);
  dim3 g8(A / 2048, B);
  if (cached) {
    k_main<true><<<gmain, 256, 0, stream>>>(loc, conf, gt, anchors, acc, keys, A);
    for (int pass = 0; pass < 4; ++pass) {
      int shift = 24 - 8 * pass;
      unsigned int himask = (pass == 0) ? 0u : (0xFFFFFFFFu << (shift + 8));
      k_hist<true><<<g8, 256, 0, stream>>>(keys, conf, gt, anchors, acc, ghist,
                                           A, shift, himask);
      k_pick<<<B, 256, 0, stream>>>(acc, ghist, A, shift, pass == 0);
    }
    k_neg<true><<<g8, 256, 0, stream>>>(keys, conf, gt, anchors, acc, A);
  } else {
    k_main<false><<<gmain, 256, 0, stream>>>(loc, conf, gt, anchors, acc, keys, A);
    for (int pass = 0; pass < 4; ++pass) {
      int shift = 24 - 8 * pass;
      unsigned int himask = (pass == 0) ? 0u : (0xFFFFFFFFu << (shift + 8));
      k_hist<false><<<g8, 256, 0, stream>>>(keys, conf, gt, anchors, acc, ghist,
                                            A, shift, himask);
      k_pick<<<B, 256, 0, stream>>>(acc, ghist, A, shift, pass == 0);
    }
    k_neg<false><<<g8, 256, 0, stream>>>(keys, conf, gt, anchors, acc, A);
  }
  k_final<<<1, 256, 0, stream>>>(acc, out, B);
}